// Round 3
// baseline (46.439 us; speedup 1.0000x reference)
//
#include <hip/hip_runtime.h>
#include <math.h>

#define BB 64
#define AA 32
#define KK 50
#define DD 128
#define MAX_KP 50
#define EPS_CS 1e-8f
#define NVEC (3 * BB * AA)   // 6144

__device__ __forceinline__ float dot4(float4 a, float4 b) {
    return a.x * b.x + a.y * b.y + a.z * b.z + a.w * b.w;
}

// One 128-thread block per (tensor, b, a) vector. 4 sub-groups of 32 lanes;
// sub-group s gathers rows k ≡ s (mod 4) as float4 (one dwordx4 per 512B row).
// Max TLP: 6144 blocks -> 12288 waves (32/CU cap) for the latency-bound gather.
__global__ __launch_bounds__(128) void embed_norm_kernel(
    const int* __restrict__ src, const int* __restrict__ pos,
    const int* __restrict__ neg, const float* __restrict__ table,
    float* __restrict__ out, unsigned* __restrict__ counter)
{
    if (blockIdx.x == 0 && threadIdx.x == 0) *counter = 0u;  // for loss tail

    const int vec = blockIdx.x;          // 0 .. 6143
    const int t   = vec >> 11;           // / (BB*AA = 2048)
    const int ba  = vec & 2047;
    const int* idx = ((t == 0) ? src : (t == 1) ? pos : neg) + ba * KK;

    __shared__ int    s_idx[KK];
    __shared__ float4 s_part[32];

    if (threadIdx.x < KK) s_idx[threadIdx.x] = idx[threadIdx.x];
    __syncthreads();

    const int lane = threadIdx.x & 31;   // float4 slot within the 128-f row
    const int sub  = threadIdx.x >> 5;   // 0..3: which k-residue class

    const float4* tab4 = (const float4*)table;
    float4 acc = make_float4(0.f, 0.f, 0.f, 0.f);
    #pragma unroll
    for (int i = 0; i < 13; ++i) {
        const int k = sub + 4 * i;
        if (k < KK) {                    // wave-uniform tail (subs 2,3 skip i=12)
            const int row = s_idx[k];    // 2-address LDS broadcast per wave
            const float4 v = tab4[row * 32 + lane];
            acc.x += v.x; acc.y += v.y; acc.z += v.z; acc.w += v.w;
        }
    }

    // combine sub pairs within each wave (lane i <-> i^32 holds same slot)
    acc.x += __shfl_xor(acc.x, 32, 64);
    acc.y += __shfl_xor(acc.y, 32, 64);
    acc.z += __shfl_xor(acc.z, 32, 64);
    acc.w += __shfl_xor(acc.w, 32, 64);

    // wave1 (subs 2+3) hands its partial to wave0 via LDS
    if (threadIdx.x >= 64 && threadIdx.x < 96) s_part[lane] = acc;
    __syncthreads();

    if (threadIdx.x < 32) {
        const float4 p = s_part[lane];
        acc.x += p.x; acc.y += p.y; acc.z += p.z; acc.w += p.w;
        const float s = 1.0f / MAX_KP;
        acc.x *= s; acc.y *= s; acc.z *= s; acc.w *= s;

        float sq = dot4(acc, acc);
        #pragma unroll
        for (int off = 16; off > 0; off >>= 1) sq += __shfl_xor(sq, off, 32);

        const float inv = 1.0f / fmaxf(sqrtf(sq), EPS_CS);
        acc.x *= inv; acc.y *= inv; acc.z *= inv; acc.w *= inv;

        ((float4*)out)[vec * 32 + lane] = acc;
    }
}

// One block per batch. LDS-staged src/pos/neg (rows padded to 132 floats:
// 16B-aligned b128 reads, <=2-way conflicts). Each thread: 2x2 (i,j) tile for
// pos AND neg. Last block (agent-scope counter) computes the mean into d_out.
__global__ __launch_bounds__(256) void cosine_loss_kernel(
    const float* __restrict__ embs, float* __restrict__ per_batch,
    unsigned* __restrict__ counter, float* __restrict__ out)
{
    const int b   = blockIdx.x;
    const int tid = threadIdx.x;

    __shared__ float s_src[AA][DD + 4];
    __shared__ float s_pos[AA][DD + 4];
    __shared__ float s_neg[AA][DD + 4];

    const float4* src4 = (const float4*)(embs + (long)b * AA * DD);
    const float4* pos4 = (const float4*)(embs + (long)(BB + b) * AA * DD);
    const float4* neg4 = (const float4*)(embs + (long)(2 * BB + b) * AA * DD);

    for (int i = tid; i < AA * DD / 4; i += 256) {   // 1024 float4s each
        const int r = i >> 5, c = i & 31;
        *(float4*)&s_src[r][c * 4] = src4[i];
        *(float4*)&s_pos[r][c * 4] = pos4[i];
        *(float4*)&s_neg[r][c * 4] = neg4[i];
    }
    __syncthreads();

    const int ib = tid >> 4;     // rows ib, ib+16
    const int jb = tid & 15;     // cols jb, jb+16

    float dp00 = 0, dp01 = 0, dp10 = 0, dp11 = 0;
    float dn00 = 0, dn01 = 0, dn10 = 0, dn11 = 0;
    #pragma unroll 8
    for (int d0 = 0; d0 < DD; d0 += 4) {
        const float4 a0 = *(const float4*)&s_src[ib][d0];
        const float4 a1 = *(const float4*)&s_src[ib + 16][d0];
        const float4 p0 = *(const float4*)&s_pos[jb][d0];
        const float4 p1 = *(const float4*)&s_pos[jb + 16][d0];
        const float4 n0 = *(const float4*)&s_neg[jb][d0];
        const float4 n1 = *(const float4*)&s_neg[jb + 16][d0];
        dp00 += dot4(a0, p0); dp01 += dot4(a0, p1);
        dp10 += dot4(a1, p0); dp11 += dot4(a1, p1);
        dn00 += dot4(a0, n0); dn01 += dot4(a0, n1);
        dn10 += dot4(a1, n0); dn11 += dot4(a1, n1);
    }

    float pmax = fmaxf(fmaxf(dp00, dp01), fmaxf(dp10, dp11));
    float nmax = fmaxf(fmaxf(dn00, dn01), fmaxf(dn10, dn11));

    #pragma unroll
    for (int off = 32; off > 0; off >>= 1) {
        pmax = fmaxf(pmax, __shfl_xor(pmax, off, 64));
        nmax = fmaxf(nmax, __shfl_xor(nmax, off, 64));
    }
    __shared__ float sp[4], sn[4];
    const int wave = tid >> 6;
    if ((tid & 63) == 0) { sp[wave] = pmax; sn[wave] = nmax; }
    __syncthreads();

    if (tid == 0) {
        const float P = fmaxf(fmaxf(sp[0], sp[1]), fmaxf(sp[2], sp[3]));
        const float N = fmaxf(fmaxf(sn[0], sn[1]), fmaxf(sn[2], sn[3]));
        const float x = P - N;
        const float l = (x >= 0.f) ? log1pf(expf(-x)) : (-x + log1pf(expf(x)));

        __hip_atomic_store(&per_batch[b], l, __ATOMIC_RELEASE,
                           __HIP_MEMORY_SCOPE_AGENT);
        const unsigned old = __hip_atomic_fetch_add(
            counter, 1u, __ATOMIC_ACQ_REL, __HIP_MEMORY_SCOPE_AGENT);
        if (old == BB - 1) {   // last block: fixed-order sum -> deterministic
            float acc = 0.f;
            for (int i = 0; i < BB; ++i)
                acc += __hip_atomic_load(&per_batch[i], __ATOMIC_ACQUIRE,
                                         __HIP_MEMORY_SCOPE_AGENT);
            out[0] = acc * (1.0f / BB);
            __hip_atomic_store(counter, 0u, __ATOMIC_RELAXED,
                               __HIP_MEMORY_SCOPE_AGENT);
        }
    }
}

extern "C" void kernel_launch(void* const* d_in, const int* in_sizes, int n_in,
                              void* d_out, int out_size, void* d_ws, size_t ws_size,
                              hipStream_t stream) {
    const int*   batch_source = (const int*)d_in[0];
    const int*   pos_result   = (const int*)d_in[1];
    const int*   neg_result   = (const int*)d_in[2];
    const float* emb_table    = (const float*)d_in[3];
    float* out = (float*)d_out;

    float*    embs      = (float*)d_ws;                  // 3*64*32*128 f32 = 3 MB
    float*    per_batch = embs + 3L * BB * AA * DD;      // 64 f32
    unsigned* counter   = (unsigned*)(per_batch + BB);   // 1 u32

    embed_norm_kernel<<<NVEC, 128, 0, stream>>>(
        batch_source, pos_result, neg_result, emb_table, embs, counter);
    cosine_loss_kernel<<<BB, 256, 0, stream>>>(embs, per_batch, counter, out);
}

// Round 4
// 34.506 us; speedup vs baseline: 1.3458x; 1.3458x over previous
//
#include <hip/hip_runtime.h>
#include <math.h>

#define BB 64
#define AA 32
#define KK 50
#define DD 128
#define MAX_KP 50
#define EPS_CS 1e-8f
#define NVEC (3 * BB * AA)   // 6144

__device__ __forceinline__ float dot4(float4 a, float4 b) {
    return a.x * b.x + a.y * b.y + a.z * b.z + a.w * b.w;
}

// One 128-thread block per (tensor, b, a) vector. Wave w handles rows
// k = 2i + w (25 rows); each row is one global_load_dwordx2 per wave
// (64 lanes x 8B = 512B row). Indices are read at wave-uniform (SGPR)
// addresses via readfirstlane -> s_load, so all 25 row loads are
// independent and issue back-to-back (100 cache lines in flight/block).
__global__ __launch_bounds__(128) void embed_norm_kernel(
    const int* __restrict__ src, const int* __restrict__ pos,
    const int* __restrict__ neg, const float* __restrict__ table,
    float* __restrict__ out)
{
    const int vec = blockIdx.x;          // 0 .. 6143
    const int t   = vec >> 11;           // / (BB*AA = 2048)
    const int ba  = vec & 2047;
    const int* idx = ((t == 0) ? src : (t == 1) ? pos : neg) + ba * KK;

    const int l = threadIdx.x & 63;                                   // float2 slot
    const int w = __builtin_amdgcn_readfirstlane(threadIdx.x >> 6);   // wave id (SGPR)

    const float2* tab2 = (const float2*)table;
    float2 acc = make_float2(0.f, 0.f);
    #pragma unroll
    for (int i = 0; i < KK / 2; ++i) {
        const int row = idx[2 * i + w];          // uniform addr -> s_load
        const float2 v = tab2[(long)row * 64 + l];
        acc.x += v.x; acc.y += v.y;
    }

    // wave1 hands its partial to wave0 via LDS
    __shared__ float2 s_part[64];
    if (threadIdx.x >= 64) s_part[l] = acc;
    __syncthreads();

    if (threadIdx.x < 64) {
        const float2 p = s_part[l];
        acc.x = (acc.x + p.x) * (1.0f / MAX_KP);
        acc.y = (acc.y + p.y) * (1.0f / MAX_KP);

        float sq = acc.x * acc.x + acc.y * acc.y;
        #pragma unroll
        for (int off = 32; off > 0; off >>= 1) sq += __shfl_xor(sq, off, 64);

        const float inv = 1.0f / fmaxf(sqrtf(sq), EPS_CS);
        acc.x *= inv; acc.y *= inv;

        ((float2*)out)[(long)vec * 64 + l] = acc;
    }
}

// 4 blocks per batch: q = {pos/neg} x {i-half}. Each block stages 16 src rows
// + 32 tgt rows (rows padded to 132 floats -> b128 reads, <=2-way conflicts),
// computes max over its 16x32 dots, writes a partial max.
__global__ __launch_bounds__(256) void cosine_part_kernel(
    const float* __restrict__ embs, float* __restrict__ part /* [BB][4] */)
{
    const int blk = blockIdx.x;          // 0..255
    const int b   = blk >> 2;
    const int q   = blk & 3;
    const int tens  = q >> 1;            // 0 = pos, 1 = neg
    const int ihalf = q & 1;             // which 16 src rows
    const int tid = threadIdx.x;

    __shared__ float s_src[16][DD + 4];
    __shared__ float s_tgt[AA][DD + 4];

    const float4* src4 = (const float4*)(embs + ((long)b * AA + ihalf * 16) * DD);
    const float4* tgt4 = (const float4*)(embs + (long)(BB + tens * BB + b) * AA * DD);

    for (int i = tid; i < 16 * DD / 4; i += 256) {   // 512 float4s
        const int r = i >> 5, c = i & 31;
        *(float4*)&s_src[r][c * 4] = src4[i];
    }
    for (int i = tid; i < AA * DD / 4; i += 256) {   // 1024 float4s
        const int r = i >> 5, c = i & 31;
        *(float4*)&s_tgt[r][c * 4] = tgt4[i];
    }
    __syncthreads();

    const int si = tid >> 4;             // 0..15 src row
    const int j  = tid & 15;             // tgt cols j, j+16

    float d0s = 0.f, d1s = 0.f;
    #pragma unroll 8
    for (int d0 = 0; d0 < DD; d0 += 4) {
        const float4 a  = *(const float4*)&s_src[si][d0];
        const float4 t0 = *(const float4*)&s_tgt[j][d0];
        const float4 t1 = *(const float4*)&s_tgt[j + 16][d0];
        d0s += dot4(a, t0);
        d1s += dot4(a, t1);
    }
    float m = fmaxf(d0s, d1s);

    #pragma unroll
    for (int off = 32; off > 0; off >>= 1) m = fmaxf(m, __shfl_xor(m, off, 64));
    __shared__ float sm[4];
    if ((tid & 63) == 0) sm[tid >> 6] = m;
    __syncthreads();

    if (tid == 0)
        part[blk] = fmaxf(fmaxf(sm[0], sm[1]), fmaxf(sm[2], sm[3]));
}

// One wave: lane b -> loss_b, wave-reduce fixed-order sum -> mean.
__global__ void finalize_kernel(const float* __restrict__ part,
                                float* __restrict__ out)
{
    const int b = threadIdx.x;           // 0..63
    const float P = fmaxf(part[b * 4 + 0], part[b * 4 + 1]);
    const float N = fmaxf(part[b * 4 + 2], part[b * 4 + 3]);
    const float x = P - N;
    float l = (x >= 0.f) ? log1pf(expf(-x)) : (-x + log1pf(expf(x)));
    #pragma unroll
    for (int off = 32; off > 0; off >>= 1) l += __shfl_xor(l, off, 64);
    if (b == 0) out[0] = l * (1.0f / BB);
}

extern "C" void kernel_launch(void* const* d_in, const int* in_sizes, int n_in,
                              void* d_out, int out_size, void* d_ws, size_t ws_size,
                              hipStream_t stream) {
    const int*   batch_source = (const int*)d_in[0];
    const int*   pos_result   = (const int*)d_in[1];
    const int*   neg_result   = (const int*)d_in[2];
    const float* emb_table    = (const float*)d_in[3];
    float* out = (float*)d_out;

    float* embs = (float*)d_ws;                     // 3*64*32*128 f32 = 3 MB
    float* part = embs + 3L * BB * AA * DD;         // 256 f32

    embed_norm_kernel<<<NVEC, 128, 0, stream>>>(
        batch_source, pos_result, neg_result, emb_table, embs);
    cosine_part_kernel<<<4 * BB, 256, 0, stream>>>(embs, part);
    finalize_kernel<<<1, 64, 0, stream>>>(part, out);
}

// Round 5
// 34.373 us; speedup vs baseline: 1.3510x; 1.0039x over previous
//
#include <hip/hip_runtime.h>
#include <math.h>

#define BB 64
#define AA 32
#define KK 50
#define DD 128
#define MAX_KP 50
#define EPS_CS 1e-8f
#define NVEC (3 * BB * AA)   // 6144

__device__ __forceinline__ float dot4(float4 a, float4 b) {
    return a.x * b.x + a.y * b.y + a.z * b.z + a.w * b.w;
}

// One 64-lane wave per (tensor, b, a) vector; 2 waves per 128-thread block.
// Gather instruction i loads TWO rows at once via per-lane addresses:
// lanes 0-31 read row idx[2i], lanes 32-63 read row idx[2i+1], 16B/lane
// (global_load_dwordx4, 1024B per instruction). Indices come from scalar
// (SGPR) loads; row select is one v_cndmask. 25 loads/wave for 50 rows.
__global__ __launch_bounds__(128) void embed_norm_kernel(
    const int* __restrict__ src, const int* __restrict__ pos,
    const int* __restrict__ neg, const float* __restrict__ table,
    float* __restrict__ out)
{
    const int vec = __builtin_amdgcn_readfirstlane(
        (blockIdx.x << 1) | (threadIdx.x >> 6));   // 0..6143, wave-uniform
    const int t  = vec >> 11;                      // / (BB*AA = 2048)
    const int ba = vec & 2047;
    const int* idx = ((t == 0) ? src : (t == 1) ? pos : neg) + ba * KK;

    const int lane = threadIdx.x & 63;
    const int half = lane >> 5;                    // 0: even rows, 1: odd rows
    const int slot = lane & 31;                    // float4 slot within the row

    const float4* tab4 = (const float4*)table;
    float4 acc = make_float4(0.f, 0.f, 0.f, 0.f);
    #pragma unroll
    for (int i = 0; i < KK / 2; ++i) {
        const int r0 = idx[2 * i];                 // SGPR (scalar load)
        const int r1 = idx[2 * i + 1];             // SGPR
        const int row = half ? r1 : r0;            // v_cndmask
        const float4 v = tab4[(row << 5) + slot];  // 32-bit offset, 16B/lane
        acc.x += v.x; acc.y += v.y; acc.z += v.z; acc.w += v.w;
    }

    // combine the two half-wave partials (each lane pairs with lane^32)
    acc.x += __shfl_xor(acc.x, 32, 64);
    acc.y += __shfl_xor(acc.y, 32, 64);
    acc.z += __shfl_xor(acc.z, 32, 64);
    acc.w += __shfl_xor(acc.w, 32, 64);

    const float s = 1.0f / MAX_KP;
    acc.x *= s; acc.y *= s; acc.z *= s; acc.w *= s;

    // norm: reduce dot4 across the 32 slots (halves already merged, so
    // xor-reduce over masks 1..16 gives the full sum in every lane)
    float sq = dot4(acc, acc);
    #pragma unroll
    for (int off = 16; off > 0; off >>= 1) sq += __shfl_xor(sq, off, 64);

    const float inv = 1.0f / fmaxf(sqrtf(sq), EPS_CS);
    acc.x *= inv; acc.y *= inv; acc.z *= inv; acc.w *= inv;

    if (lane < 32)
        ((float4*)out)[(vec << 5) + slot] = acc;
}

// 4 blocks per batch: q = {pos/neg} x {i-half}. Each block stages 16 src rows
// + 32 tgt rows (rows padded to 132 floats -> b128 reads, <=2-way conflicts),
// computes max over its 16x32 dots, writes a partial max.
__global__ __launch_bounds__(256) void cosine_part_kernel(
    const float* __restrict__ embs, float* __restrict__ part /* [BB][4] */)
{
    const int blk = blockIdx.x;          // 0..255
    const int b   = blk >> 2;
    const int q   = blk & 3;
    const int tens  = q >> 1;            // 0 = pos, 1 = neg
    const int ihalf = q & 1;             // which 16 src rows
    const int tid = threadIdx.x;

    __shared__ float s_src[16][DD + 4];
    __shared__ float s_tgt[AA][DD + 4];

    const float4* src4 = (const float4*)(embs + ((long)b * AA + ihalf * 16) * DD);
    const float4* tgt4 = (const float4*)(embs + (long)(BB + tens * BB + b) * AA * DD);

    for (int i = tid; i < 16 * DD / 4; i += 256) {   // 512 float4s
        const int r = i >> 5, c = i & 31;
        *(float4*)&s_src[r][c * 4] = src4[i];
    }
    for (int i = tid; i < AA * DD / 4; i += 256) {   // 1024 float4s
        const int r = i >> 5, c = i & 31;
        *(float4*)&s_tgt[r][c * 4] = tgt4[i];
    }
    __syncthreads();

    const int si = tid >> 4;             // 0..15 src row
    const int j  = tid & 15;             // tgt cols j, j+16

    float d0s = 0.f, d1s = 0.f;
    #pragma unroll 8
    for (int d0 = 0; d0 < DD; d0 += 4) {
        const float4 a  = *(const float4*)&s_src[si][d0];
        const float4 t0 = *(const float4*)&s_tgt[j][d0];
        const float4 t1 = *(const float4*)&s_tgt[j + 16][d0];
        d0s += dot4(a, t0);
        d1s += dot4(a, t1);
    }
    float m = fmaxf(d0s, d1s);

    #pragma unroll
    for (int off = 32; off > 0; off >>= 1) m = fmaxf(m, __shfl_xor(m, off, 64));
    __shared__ float sm[4];
    if ((tid & 63) == 0) sm[tid >> 6] = m;
    __syncthreads();

    if (tid == 0)
        part[blk] = fmaxf(fmaxf(sm[0], sm[1]), fmaxf(sm[2], sm[3]));
}

// One wave: lane b -> loss_b, wave-reduce fixed-order sum -> mean.
__global__ void finalize_kernel(const float* __restrict__ part,
                                float* __restrict__ out)
{
    const int b = threadIdx.x;           // 0..63
    const float P = fmaxf(part[b * 4 + 0], part[b * 4 + 1]);
    const float N = fmaxf(part[b * 4 + 2], part[b * 4 + 3]);
    const float x = P - N;
    float l = (x >= 0.f) ? log1pf(expf(-x)) : (-x + log1pf(expf(x)));
    #pragma unroll
    for (int off = 32; off > 0; off >>= 1) l += __shfl_xor(l, off, 64);
    if (b == 0) out[0] = l * (1.0f / BB);
}

extern "C" void kernel_launch(void* const* d_in, const int* in_sizes, int n_in,
                              void* d_out, int out_size, void* d_ws, size_t ws_size,
                              hipStream_t stream) {
    const int*   batch_source = (const int*)d_in[0];
    const int*   pos_result   = (const int*)d_in[1];
    const int*   neg_result   = (const int*)d_in[2];
    const float* emb_table    = (const float*)d_in[3];
    float* out = (float*)d_out;

    float* embs = (float*)d_ws;                     // 3*64*32*128 f32 = 3 MB
    float* part = embs + 3L * BB * AA * DD;         // 256 f32

    embed_norm_kernel<<<NVEC / 2, 128, 0, stream>>>(
        batch_source, pos_result, neg_result, emb_table, embs);
    cosine_part_kernel<<<4 * BB, 256, 0, stream>>>(embs, part);
    finalize_kernel<<<1, 64, 0, stream>>>(part, out);
}